// Round 3
// baseline (253.880 us; speedup 1.0000x reference)
//
#include <hip/hip_runtime.h>

#define NN 4096     // nodes
#define HC 8        // heads
#define DC 32       // dim per head
#define OC 256      // out channels = HC*DC
#define KC 256      // in channels
#define CF 6        // curvature features

typedef _Float16 f16_t;
typedef f16_t f16x8 __attribute__((ext_vector_type(8)));
typedef float f32x4 __attribute__((ext_vector_type(4)));
typedef float f32x2 __attribute__((ext_vector_type(2)));
typedef unsigned u32x2 __attribute__((ext_vector_type(2)));

#if defined(__has_builtin)
#if __has_builtin(__builtin_amdgcn_exp2f)
#define EXP2F(x) __builtin_amdgcn_exp2f(x)
#else
#define EXP2F(x) exp2f(x)
#endif
#else
#define EXP2F(x) exp2f(x)
#endif

// ---------------------------------------------------------------------------
// Kernel 1a: h-GEMM prep (512 blocks x 256 thr; split from prep_all in R16 so
// rocprof attributes prep time per-role — the combined prep_all was ~120us,
// 6x my roofline model, with no counters to explain why).
// Produces: e_l (f32 [i][h]), e_r (f32 [h][j], attn MFMA C-operand), V as f16
// in attn's B-fragment order (hT2[head][c][q][d32][t8]).
// R16: next-tile global loads issued between the barriers and the k-compute,
// hiding the ~500cy x/W latency under the 16-k FMA block (was fully exposed).
// ---------------------------------------------------------------------------
__global__ __launch_bounds__(256) void prep_gemm(const float* __restrict__ x,
                                                 const float* __restrict__ W,
                                                 const float* __restrict__ a_l,
                                                 const float* __restrict__ a_r,
                                                 float* __restrict__ e_l2,
                                                 float* __restrict__ erT,
                                                 f16_t* __restrict__ hT2) {
  __shared__ float As[16][68];   // [k][i]
  __shared__ float Bs[16][36];   // [k][c]
  __shared__ float Ct[DC][65];   // [c][i]
  const float LOG2E = 1.44269504088896340736f;
  const int t = threadIdx.x;
  const int bid = blockIdx.x;
  const int i0 = (bid & 63) * 64;
  const int head = bid >> 6;
  const int c0 = head * DC;
  const int tx = t & 7;          // col group (4 cols)
  const int ty = t >> 3;         // row pair (2 rows)
  const int lr = t >> 2;         // staging row 0..63
  const int lk = (t & 3) * 4;    // staging k 0,4,8,12

  float acc[2][4] = {};
  f32x4 av = *(const f32x4*)&x[(size_t)(i0 + lr) * KC + lk];
  f32x4 wv = {};
  if (t < 128) wv = *(const f32x4*)&W[(size_t)(c0 + (t >> 2)) * KC + lk];
  for (int kk = 0; kk < KC; kk += 16) {
    __syncthreads();             // prev compute done before LDS overwrite
    As[lk + 0][lr] = av[0]; As[lk + 1][lr] = av[1];
    As[lk + 2][lr] = av[2]; As[lk + 3][lr] = av[3];
    if (t < 128) {
      int br = t >> 2;
      Bs[lk + 0][br] = wv[0]; Bs[lk + 1][br] = wv[1];
      Bs[lk + 2][br] = wv[2]; Bs[lk + 3][br] = wv[3];
    }
    __syncthreads();
    if (kk + 16 < KC) {          // prefetch next tile; latency hidden by FMAs
      av = *(const f32x4*)&x[(size_t)(i0 + lr) * KC + kk + 16 + lk];
      if (t < 128) wv = *(const f32x4*)&W[(size_t)(c0 + (t >> 2)) * KC + kk + 16 + lk];
    }
#pragma unroll
    for (int k = 0; k < 16; ++k) {
      f32x2 a = *(const f32x2*)&As[k][ty * 2];
      f32x4 b = *(const f32x4*)&Bs[k][tx * 4];
#pragma unroll
      for (int r = 0; r < 2; ++r)
#pragma unroll
        for (int u = 0; u < 4; ++u)
          acc[r][u] += a[r] * b[u];
    }
  }

  // e_l (f32 [i][h]) / e_r (f32 [h][j]); reduce across 8 tx lanes
  f32x4 al4 = *(const f32x4*)&a_l[c0 + tx * 4];
  f32x4 ar4 = *(const f32x4*)&a_r[c0 + tx * 4];
#pragma unroll
  for (int r = 0; r < 2; ++r) {
    float el = acc[r][0] * al4[0] + acc[r][1] * al4[1] +
               acc[r][2] * al4[2] + acc[r][3] * al4[3];
    float er = acc[r][0] * ar4[0] + acc[r][1] * ar4[1] +
               acc[r][2] * ar4[2] + acc[r][3] * ar4[3];
    el += __shfl_xor(el, 1, 64); el += __shfl_xor(el, 2, 64); el += __shfl_xor(el, 4, 64);
    er += __shfl_xor(er, 1, 64); er += __shfl_xor(er, 2, 64); er += __shfl_xor(er, 4, 64);
    if (tx == 0) {
      int j = i0 + ty * 2 + r;
      e_l2[j * HC + head] = el * LOG2E;
      erT[head * NN + j] = er * LOG2E;
    }
  }

  // transpose to B-fragment layout via LDS; store V as f16 (better than bf16)
#pragma unroll
  for (int r = 0; r < 2; ++r)
#pragma unroll
    for (int u = 0; u < 4; ++u)
      Ct[tx * 4 + u][ty * 2 + r] = acc[r][u];
  __syncthreads();
  const size_t base = (size_t)head * (NN / 32) * 1024 + (size_t)(bid & 63) * 2048;
#pragma unroll
  for (int rep = 0; rep < 8; ++rep) {
    int idx = rep * 256 + t;                 // enumerates [chunkL][q][d][t8]
    int dd = (idx >> 3) & 31;
    int jl = (idx >> 10) * 32 + ((idx >> 8) & 3) * 8 + (idx & 7);
    hT2[base + idx] = (f16_t)Ct[dd][jl];
  }
}

// ---------------------------------------------------------------------------
// Kernel 1b: pack prep (2048 blocks x 256 thr). Ballot-packs adj -> 2MB
// bitmask; cfH (f16 rows [j][8], f<6 valid, padded 0) for the bias-MFMA
// B-operand; wcA = block-diagonal wc*gate*LOG2E constant in f16 A-fragment
// layout. R16: ballot loop fully unrolled with batched loads (32 independent
// dword loads in flight before the ballot chain) — the R15 form serialized
// 32 x ~500-900cy load->ballot->store chains per wave.
// ---------------------------------------------------------------------------
__global__ __launch_bounds__(256) void prep_pack(const int* __restrict__ adj,
                                                 const float* __restrict__ cfeat,
                                                 const float* __restrict__ Wc,
                                                 const float* __restrict__ gate,
                                                 unsigned* __restrict__ adjb,
                                                 f16_t* __restrict__ cfH,
                                                 f16_t* __restrict__ wcA) {
  const float LOG2E = 1.44269504088896340736f;
  const int t = threadIdx.x;
  const int pb = blockIdx.x;
  const int ptid = pb * 256 + t;
  const int lane = t & 63;
  const int wv = pb * 4 + (t >> 6);            // 0..8191

  int v[32];
#pragma unroll
  for (int u = 0; u < 32; ++u) {
    int g = wv * 32 + u;                       // segment id
    v[u] = adj[(size_t)(g >> 6) * NN + (g & 63) * 64 + lane];
  }
#pragma unroll
  for (int u = 0; u < 32; ++u) {
    int g = wv * 32 + u;
    unsigned long long m = __ballot(v[u] > 0);
    if (lane == 0) *(unsigned long long*)(adjb + (g >> 6) * 128 + (g & 63) * 2) = m;
  }

  if (ptid < NN) {
    int j = ptid;
#pragma unroll
    for (int f = 0; f < CF; ++f) cfH[j * 8 + f] = (f16_t)cfeat[j * CF + f];
    cfH[j * 8 + 6] = (f16_t)0.f;
    cfH[j * 8 + 7] = (f16_t)0.f;
  }
  if (ptid < 128) {
    int ln = ptid & 63, hg = ptid >> 6;
    int row = ln & 15, jjp = ln >> 4;
    int hl = row >> 2, jj = row & 3;
    float gs = gate[0] * LOG2E;
#pragma unroll
    for (int e = 0; e < 8; ++e) {
      float vv = (jj == jjp && e < CF) ? Wc[(hg * 4 + hl) * CF + e] * gs : 0.f;
      wcA[(hg * 64 + ln) * 8 + e] = (f16_t)vv;
    }
  }
}

// ---------------------------------------------------------------------------
// Kernel 2: fused masked attention. R16 on top of R15's MFMA-bias structure:
// R15 post-mortem: dur 110->127 despite VALUBusy 64->38% — latency-bound
// (VGPR=56: compiler serialized the per-m cfR/erT L2 loads, ~8 exposed
// ~200cy round-trips per chunk; R13's cross-chunk prefetch was lost).
// R16 fixes:
//  (1) batch ALL 8 m-iterations' cj/er loads at chunk top (cjb/erb, 64 VGPR
//      of buffers -> est ~120 total, under the lb(512,4) 128 cap): one L2
//      latency per chunk amortized over ~1000cy of issue.
//  (2) fp16 curvature path: |cf_i-cf_j| via v_pk_sub/max_f16 (4+4 pk ops vs
//      ~18 scalar f32 + cvt), feeding mfma_f32_16x16x32_f16. fp16 (2^-11)
//      is MORE precise than R15's bf16 (2^-8) here.
//  (3) P and V in fp16 (same MFMA rate as bf16, ~8x less quantization error;
//      P in [2^-8, 2^8], V +-4 — well within fp16 range; absmax should DROP).
// LDS P-exchange swizzle unchanged (bank conflicts were only ~4% of cycles).
// Failure signals: WRITE_SIZE >> 4MB = spill; absmax rise = layout bug.
// ---------------------------------------------------------------------------
__global__ __launch_bounds__(512, 4) void attn(const unsigned* __restrict__ adjb,
                                               const float* __restrict__ e_l2,
                                               const float* __restrict__ erT,
                                               const f16_t* __restrict__ cfH,
                                               const f16_t* __restrict__ wcA,
                                               const f16_t* __restrict__ hT2,
                                               float* __restrict__ out) {
  __shared__ unsigned Pl[8][1024];   // per-wave P exchange: [hl(4)][i(16)][p(16)]
  __shared__ float Obuf[16][128];
  __shared__ float Sbuf[16][4];
  const int tid = threadIdx.x;
  const int w = tid >> 6;        // 0..7: wave owns chunks c == w (mod 8)
  const int lane = tid & 63;
  const int il = lane & 15;      // bias: i (local); PV: d-index
  const int q = lane >> 4;       // bias: head-local; PV: j-slice quad
  const int ibase = blockIdx.x * 16;
  const int hg = blockIdx.y;     // head quad: heads hg*4 .. hg*4+3
  const int i = ibase + il;
  const int h = hg * 4 + q;      // this lane's bias-head
  const int HSTRIDE = (NN / 32) * 1024;

  for (int idx = tid; idx < 16 * 128; idx += 512) (&Obuf[0][0])[idx] = 0.f;
  if (tid < 64) (&Sbuf[0][0])[tid] = 0.f;
  __syncthreads();

  // lane constants
  const f16x8 cfiH = *(const f16x8*)&cfH[(size_t)i * 8];
  const float elv = e_l2[i * HC + h];
  const f32x4 ev4 = (f32x4){elv, elv, elv, elv};
  const f16x8 wA = *(const f16x8*)&wcA[(hg * 64 + lane) * 8];
  const unsigned* adjrow = adjb + i * 128;
  unsigned* Pw = &Pl[w][0];

  f32x4 acc[4][2];
#pragma unroll
  for (int hl = 0; hl < 4; ++hl)
#pragma unroll
    for (int d = 0; d < 2; ++d) acc[hl][d] = (f32x4){0.f, 0.f, 0.f, 0.f};
  f32x2 S2 = (f32x2){0.f, 0.f};

  unsigned mc = adjrow[w];     // mask prefetch
  for (int c = w; c < NN / 32; c += 8) {
    const unsigned madj = mc;
    mc = adjrow[(c + 8) & (NN / 32 - 1)];
    const int j0c = c * 32;

    // ---- batched loads for all 8 m's: one L2 round-trip per chunk ----
    f16x8 cjb[8];
#pragma unroll
    for (int m = 0; m < 8; ++m)
      cjb[m] = *(const f16x8*)&cfH[(size_t)(j0c + m * 4 + q) * 8];
    f32x4 erb[8];
#pragma unroll
    for (int m = 0; m < 8; ++m)
      erb[m] = *(const f32x4*)&erT[(size_t)h * NN + j0c + m * 4];

    // -------- stage 1: 8 bias-MFMAs (4 j's x 4 heads x 16 i each) --------
#pragma unroll
    for (int m = 0; m < 8; ++m) {
      f16x8 df = cfiH - cjb[m];                         // 4x v_pk_sub_f16
      f16x8 uf = __builtin_elementwise_max(df, -df);    // 4x v_pk_max_f16

      f32x4 sv = erb[m] + ev4;                          // C: leaky(el+er), f32
      f32x4 cin = __builtin_elementwise_max(sv, 0.2f * sv);
      f32x4 dD = __builtin_amdgcn_mfma_f32_16x16x32_f16(wA, uf, cin, 0, 0, 0);

      const unsigned mb = (madj >> (m * 4)) & 0xfu;
      f32x4 pv;
#pragma unroll
      for (int r = 0; r < 4; ++r)
        pv[r] = ((mb >> r) & 1u) ? EXP2F(dD[r]) : 0.f;
      S2 += (f32x2){pv[0], pv[1]} + (f32x2){pv[2], pv[3]};

      union { f16_t hh[2]; unsigned u; } w0, w1;
      w0.hh[0] = (f16_t)pv[0]; w0.hh[1] = (f16_t)pv[1];
      w1.hh[0] = (f16_t)pv[2]; w1.hh[1] = (f16_t)pv[3];
      // store j-pairs 2m,2m+1 for head-local q; p XOR-swizzled for banks
      const int off = (q * 16 + il) * 16 + ((2 * m) ^ (((il + q) & 3) << 2));
      *(u32x2*)(Pw + off) = (u32x2){w0.u, w1.u};
    }

    // -------- stage 2: PV (same-wave DS ordering; no barrier) --------
#pragma unroll
    for (int hl = 0; hl < 4; ++hl) {
      const int roff = (hl * 16 + il) * 16 + ((q * 4) ^ (((il + hl) & 3) << 2));
      f16x8 af = *(const f16x8*)(Pw + roff);
      const f16_t* bp = hT2 + (size_t)(hg * 4 + hl) * HSTRIDE + c * 1024 + q * 256 + il * 8;
      f16x8 b0 = *(const f16x8*)bp;
      f16x8 b1 = *(const f16x8*)(bp + 128);
      acc[hl][0] = __builtin_amdgcn_mfma_f32_16x16x32_f16(af, b0, acc[hl][0], 0, 0, 0);
      acc[hl][1] = __builtin_amdgcn_mfma_f32_16x16x32_f16(af, b1, acc[hl][1], 0, 0, 0);
    }
  }

  // S: lane (q,il) owns head q fully for its chunks -> one atomic per lane
  atomicAdd(&Sbuf[il][q], S2[0] + S2[1]);
  // O partials: PV C/D layout row = q*4+r (i), col = il (d half)
#pragma unroll
  for (int hl = 0; hl < 4; ++hl)
#pragma unroll
    for (int dh = 0; dh < 2; ++dh)
#pragma unroll
      for (int r = 0; r < 4; ++r)
        atomicAdd(&Obuf[q * 4 + r][hl * DC + dh * 16 + il], acc[hl][dh][r]);
  __syncthreads();

  // epilogue: divide by softmax denom, coalesced store
  for (int idx = tid; idx < 16 * 128; idx += 512) {
    int row = idx >> 7;
    int colg = idx & 127;
    out[(size_t)(ibase + row) * OC + hg * 128 + colg] =
        Obuf[row][colg] / Sbuf[row][colg >> 5];
  }
}

// ---------------------------------------------------------------------------
extern "C" void kernel_launch(void* const* d_in, const int* in_sizes, int n_in,
                              void* d_out, int out_size, void* d_ws, size_t ws_size,
                              hipStream_t stream) {
  const float* x    = (const float*)d_in[0];
  // d_in[1] = positions — unused by the reference
  const float* cfeat= (const float*)d_in[2];
  const int*   adj  = (const int*)d_in[3];
  const float* W    = (const float*)d_in[4];
  const float* a_l  = (const float*)d_in[5];
  const float* a_r  = (const float*)d_in[6];
  const float* Wc   = (const float*)d_in[7];
  const float* gate = (const float*)d_in[8];
  float* out = (float*)d_out;

  char* ws = (char*)d_ws;
  f16_t*    hT2  = (f16_t*)ws;                               // 2 MB
  unsigned* adjb = (unsigned*)(ws + (2u << 20));             // 2 MB
  float*    e_l2 = (float*)(ws + (4u << 20));                // 128 KB
  float*    erT  = (float*)(ws + (4u << 20) + (128u << 10)); // 128 KB
  f16_t*    cfH  = (f16_t*)(ws + (4u << 20) + (256u << 10)); // 64 KB
  f16_t*    wcA  = (f16_t*)(ws + (4u << 20) + (320u << 10)); // 2 KB

  prep_gemm<<<512, 256, 0, stream>>>(x, W, a_l, a_r, e_l2, erT, hT2);
  prep_pack<<<2048, 256, 0, stream>>>(adj, cfeat, Wc, gate, adjb, cfH, wcA);
  attn<<<dim3(NN / 16, 2), 512, 0, stream>>>(adjb, e_l2, erT, cfH, wcA,
                                             hT2, out);
}

// Round 5
// 187.533 us; speedup vs baseline: 1.3538x; 1.3538x over previous
//
#include <hip/hip_runtime.h>

#define NN 4096     // nodes
#define HC 8        // heads
#define DC 32       // dim per head
#define OC 256      // out channels = HC*DC
#define KC 256      // in channels
#define CF 6        // curvature features

typedef _Float16 f16_t;
typedef f16_t f16x2 __attribute__((ext_vector_type(2)));
typedef f16_t f16x8 __attribute__((ext_vector_type(8)));
typedef __fp16 hh2 __attribute__((ext_vector_type(2)));   // builtin return type
typedef float f32x4 __attribute__((ext_vector_type(4)));
typedef float f32x2 __attribute__((ext_vector_type(2)));
typedef unsigned u32x4 __attribute__((ext_vector_type(4)));

#if defined(__has_builtin)
#if __has_builtin(__builtin_amdgcn_exp2f)
#define EXP2F(x) __builtin_amdgcn_exp2f(x)
#else
#define EXP2F(x) exp2f(x)
#endif
#else
#define EXP2F(x) exp2f(x)
#endif

union HU { f16x2 h; unsigned u; };

// ---------------------------------------------------------------------------
// Kernel 1: heterogeneous prep (R13 monolith restored for block-level overlap
// between roles; two sequential launches can't overlap on one stream).
// Blocks 0..511 (gemm role): h-GEMM (64 rows x 1 head) + e_l (f32 [i][h]) +
//   e_r packed f16 in attn lane order (erP[c][q][h][t8], pre-scaled LOG2E) +
//   V as f16 in attn's B-fragment order (hT2[head][c][q][d32][t8]).
//   R16's cross-tile global prefetch kept (x/W latency hidden under FMAs).
// Blocks 512..2559 (pack role): ballot-pack adj -> 2MB bitmask (R16 batched
//   loads kept); cfT (f32, i-side) + cfP packed f16 in attn lane order
//   (cfP[c][q][f][t8]); Wc2 = Wc*gate*LOG2E (f32).
// ---------------------------------------------------------------------------
__global__ __launch_bounds__(256) void prep_all(const float* __restrict__ x,
                                                const float* __restrict__ W,
                                                const float* __restrict__ a_l,
                                                const float* __restrict__ a_r,
                                                const int* __restrict__ adj,
                                                const float* __restrict__ cfeat,
                                                const float* __restrict__ Wc,
                                                const float* __restrict__ gate,
                                                float* __restrict__ e_l2,
                                                f16_t* __restrict__ erP,
                                                f16_t* __restrict__ hT2,
                                                unsigned* __restrict__ adjb,
                                                float* __restrict__ cfT,
                                                f16_t* __restrict__ cfP,
                                                float* __restrict__ Wc2) {
  __shared__ float As[16][68];   // [k][i]
  __shared__ float Bs[16][36];   // [k][c]
  __shared__ float Ct[DC][65];   // [c][i]
  const float LOG2E = 1.44269504088896340736f;
  const int t = threadIdx.x;
  const int bid = blockIdx.x;

  if (bid >= 512) {
    // ---------------- pack role ----------------
    const int pb = bid - 512;                    // 0..2047
    const int ptid = pb * 256 + t;
    const int lane = t & 63;
    const int wv = pb * 4 + (t >> 6);            // 0..8191
    int v[32];
#pragma unroll
    for (int u = 0; u < 32; ++u) {
      int g = wv * 32 + u;                       // segment id
      v[u] = adj[(size_t)(g >> 6) * NN + (g & 63) * 64 + lane];
    }
#pragma unroll
    for (int u = 0; u < 32; ++u) {
      int g = wv * 32 + u;
      unsigned long long m = __ballot(v[u] > 0);
      if (lane == 0) *(unsigned long long*)(adjb + (g >> 6) * 128 + (g & 63) * 2) = m;
    }
    if (ptid < NN * CF) {
      int j = ptid / CF, f = ptid - j * CF;
      float vv = cfeat[ptid];
      cfT[f * NN + j] = vv;
      int cc = j >> 5, qq = (j >> 3) & 3, tt = j & 7;
      cfP[((cc * 4 + qq) * CF + f) * 8 + tt] = (f16_t)vv;
    }
    if (ptid < HC * CF) Wc2[ptid] = Wc[ptid] * gate[0] * LOG2E;
    return;
  }

  // ---------------- gemm role ----------------
  const int i0 = (bid & 63) * 64;
  const int head = bid >> 6;
  const int c0 = head * DC;
  const int tx = t & 7;          // col group (4 cols)
  const int ty = t >> 3;         // row pair (2 rows)
  const int lr = t >> 2;         // staging row 0..63
  const int lk = (t & 3) * 4;    // staging k 0,4,8,12

  float acc[2][4] = {};
  f32x4 av = *(const f32x4*)&x[(size_t)(i0 + lr) * KC + lk];
  f32x4 wv = {};
  if (t < 128) wv = *(const f32x4*)&W[(size_t)(c0 + (t >> 2)) * KC + lk];
  for (int kk = 0; kk < KC; kk += 16) {
    __syncthreads();             // prev compute done before LDS overwrite
    As[lk + 0][lr] = av[0]; As[lk + 1][lr] = av[1];
    As[lk + 2][lr] = av[2]; As[lk + 3][lr] = av[3];
    if (t < 128) {
      int br = t >> 2;
      Bs[lk + 0][br] = wv[0]; Bs[lk + 1][br] = wv[1];
      Bs[lk + 2][br] = wv[2]; Bs[lk + 3][br] = wv[3];
    }
    __syncthreads();
    if (kk + 16 < KC) {          // prefetch next tile; latency hidden by FMAs
      av = *(const f32x4*)&x[(size_t)(i0 + lr) * KC + kk + 16 + lk];
      if (t < 128) wv = *(const f32x4*)&W[(size_t)(c0 + (t >> 2)) * KC + kk + 16 + lk];
    }
#pragma unroll
    for (int k = 0; k < 16; ++k) {
      f32x2 a = *(const f32x2*)&As[k][ty * 2];
      f32x4 b = *(const f32x4*)&Bs[k][tx * 4];
#pragma unroll
      for (int r = 0; r < 2; ++r)
#pragma unroll
        for (int u = 0; u < 4; ++u)
          acc[r][u] += a[r] * b[u];
    }
  }

  // e_l (f32 [i][h]) / e_r (packed f16, attn lane order); reduce across tx
  f32x4 al4 = *(const f32x4*)&a_l[c0 + tx * 4];
  f32x4 ar4 = *(const f32x4*)&a_r[c0 + tx * 4];
#pragma unroll
  for (int r = 0; r < 2; ++r) {
    float el = acc[r][0] * al4[0] + acc[r][1] * al4[1] +
               acc[r][2] * al4[2] + acc[r][3] * al4[3];
    float er = acc[r][0] * ar4[0] + acc[r][1] * ar4[1] +
               acc[r][2] * ar4[2] + acc[r][3] * ar4[3];
    el += __shfl_xor(el, 1, 64); el += __shfl_xor(el, 2, 64); el += __shfl_xor(el, 4, 64);
    er += __shfl_xor(er, 1, 64); er += __shfl_xor(er, 2, 64); er += __shfl_xor(er, 4, 64);
    if (tx == 0) {
      int j = i0 + ty * 2 + r;
      e_l2[j * HC + head] = el * LOG2E;
      int cc = j >> 5, qq = (j >> 3) & 3, tt = j & 7;
      erP[((cc * 4 + qq) * HC + head) * 8 + tt] = (f16_t)(er * LOG2E);
    }
  }

  // transpose to B-fragment layout via LDS; V stored f16
#pragma unroll
  for (int r = 0; r < 2; ++r)
#pragma unroll
    for (int u = 0; u < 4; ++u)
      Ct[tx * 4 + u][ty * 2 + r] = acc[r][u];
  __syncthreads();
  const size_t base = (size_t)head * (NN / 32) * 1024 + (size_t)(bid & 63) * 2048;
#pragma unroll
  for (int rep = 0; rep < 8; ++rep) {
    int idx = rep * 256 + t;                 // enumerates [chunkL][q][d][t8]
    int dd = (idx >> 3) & 31;
    int jl = (idx >> 10) * 32 + ((idx >> 8) & 3) * 8 + (idx & 7);
    hT2[base + idx] = (f16_t)Ct[dd][jl];
  }
}

// ---------------------------------------------------------------------------
// Kernel 2: fused masked attention. R17 = R13's measured-best skeleton
// (2 heads/block, grid (256,4), 256 thr, lb(256,4), cross-ITERATION register
// prefetch, register-resident P->MFMA, no LDS exchange) with the math moved
// to packed f16 (v_pk_* = 2 f16/lane/cyc, 2x the f32 vector rate):
//  - cf diff/abs: 6 pk_sub + 6 pk_max (replaces unpk+sub+abs, ~24 slots)
//  - bias dot: 6 pk_fma per head, accumulated FROM ZERO (f16 rounding on the
//    small bias sum only), single pk_add into leaky(el+er)
//  - leaky: pk_add + pk_mul + pk_max per head
//  - mask: v_cndmask on the f32 exp values (cvt_pkrtz(0,0)==0 -> masked P
//    exactly zero); S accumulated in f32 (2 v_add per p,h)
//  - exp: 2x v_exp_f32 + v_cvt_pkrtz (union bit-cast: builtin returns __fp16
//    vector, incompatible with _Float16 vector — R17's compile failure)
// er now f16 (2^-11) vs R13's bf16 (2^-9): logit error budget DROPS.
// R15/R16's MFMA-bias structure abandoned: its serial MFMA->exp->LDS->MFMA
// chain was latency-bound (VALU 33-38%, dur 127-139) and same-iteration
// load batching was re-sunk by the scheduler (VGPR stayed 60).
// Failure signals: WRITE_SIZE >> 4MB = spill (live set est ~116 VGPR of 128);
// absmax > 1e-3 = f16 accumulation/layout bug.
// ---------------------------------------------------------------------------
__global__ __launch_bounds__(256, 4) void attn(const unsigned* __restrict__ adjb,
                                               const float* __restrict__ e_l2,
                                               const float* __restrict__ cfT,
                                               const float* __restrict__ Wc2,
                                               const u32x4* __restrict__ cfP4,
                                               const u32x4* __restrict__ erP4,
                                               const f16_t* __restrict__ hT2,
                                               float* __restrict__ out) {
  __shared__ float Obuf[16][64];
  __shared__ float Sbuf[16][2];
  const int tid = threadIdx.x;
  const int w = tid >> 6;        // 0..3: wave owns chunks c == w (mod 4)
  const int lane = tid & 63;
  const int il = lane & 15;
  const int quad = lane >> 4;
  const int ibase = blockIdx.x * 16;
  const int hg = blockIdx.y;     // head pair: heads hg*2, hg*2+1
  const int i = ibase + il;

  for (int idx = tid; idx < 16 * 64; idx += 256) (&Obuf[0][0])[idx] = 0.f;
  if (tid < 32) (&Sbuf[0][0])[tid] = 0.f;
  __syncthreads();

  // lane constants (f16x2 duplicated pairs)
  f16x2 cfi2h[CF];
#pragma unroll
  for (int f = 0; f < CF; ++f) {
    f16_t v = (f16_t)cfT[f * NN + i];
    cfi2h[f] = (f16x2){v, v};
  }
  f16x2 elh[2];
  {
    f32x2 e0 = *(const f32x2*)&e_l2[i * HC + hg * 2];
#pragma unroll
    for (int u = 0; u < 2; ++u) { f16_t v = (f16_t)e0[u]; elh[u] = (f16x2){v, v}; }
  }
  f16x2 wch[2][CF];
#pragma unroll
  for (int h = 0; h < 2; ++h)
#pragma unroll
    for (int f = 0; f < CF; ++f) {
      f16_t v = (f16_t)Wc2[(hg * 2 + h) * CF + f];
      wch[h][f] = (f16x2){v, v};
    }
  const f16x2 lslope = (f16x2){(f16_t)0.2f, (f16_t)0.2f};

  f32x4 acc[2][2];
#pragma unroll
  for (int h = 0; h < 2; ++h)
#pragma unroll
    for (int d = 0; d < 2; ++d) acc[h][d] = (f32x4){0.f, 0.f, 0.f, 0.f};
  float S[2] = {0.f, 0.f};

  const f16_t* hTbase = hT2 + (size_t)hg * 2 * ((NN / 32) * 1024) + quad * 256 + il * 8;
  const u32x4* cfb = cfP4 + quad * CF;           // c-stride 4*CF  (u32x4 units)
  const u32x4* erb = erP4 + quad * HC + hg * 2;  // c-stride 4*HC
  const unsigned* adjrow = adjb + i * 128;

  // ---- prime the prefetch registers for chunk c = w ----
  u32x4 cfc[CF];
#pragma unroll
  for (int f = 0; f < CF; ++f) cfc[f] = cfb[w * (4 * CF) + f];
  u32x4 erc[2];
#pragma unroll
  for (int h = 0; h < 2; ++h) erc[h] = erb[w * (4 * HC) + h];
  unsigned mc = adjrow[w];

#pragma unroll 2
  for (int c = w; c < NN / 32; c += 4) {
    // V fragments: issued at body top, consumed at the end (~full-body lead)
    const f16_t* bp0 = hTbase + c * 1024;
    const f16_t* bp1 = bp0 + (NN / 32) * 1024;
    f16x8 b00 = *(const f16x8*)bp0;
    f16x8 b01 = *(const f16x8*)(bp0 + 128);
    f16x8 b10 = *(const f16x8*)bp1;
    f16x8 b11 = *(const f16x8*)(bp1 + 128);

    // ---- phase 1: args (consumes cfc/erc; all pk-f16) ----
    f16x2 arg[2][4];
#pragma unroll
    for (int p = 0; p < 4; ++p) {
      f16x2 bias0 = (f16x2){(f16_t)0.f, (f16_t)0.f};
      f16x2 bias1 = (f16x2){(f16_t)0.f, (f16_t)0.f};
#pragma unroll
      for (int f = 0; f < CF; ++f) {
        HU cu; cu.u = cfc[f][p];
        f16x2 d = cfi2h[f] - cu.h;                       // v_pk_sub_f16
        f16x2 ad = __builtin_elementwise_max(d, -d);     // v_pk_max_f16 (neg mod)
        bias0 = __builtin_elementwise_fma(ad, wch[0][f], bias0);
        bias1 = __builtin_elementwise_fma(ad, wch[1][f], bias1);
      }
#pragma unroll
      for (int h = 0; h < 2; ++h) {
        HU eu; eu.u = erc[h][p];
        f16x2 s = elh[h] + eu.h;                         // v_pk_add_f16
        f16x2 lk = __builtin_elementwise_max(s, lslope * s);
        arg[h][p] = lk + (h ? bias1 : bias0);
      }
    }
    const unsigned m8 = (mc >> (quad * 8)) & 0xffu;      // mc dead after this

    // ---- prefetch chunk c+4 (cfc/erc/mc all consumed; one body of lead) ----
    {
      const int cn = (c + 4) & (NN / 32 - 1);
#pragma unroll
      for (int f = 0; f < CF; ++f) cfc[f] = cfb[cn * (4 * CF) + f];
#pragma unroll
      for (int h = 0; h < 2; ++h) erc[h] = erb[cn * (4 * HC) + h];
      mc = adjrow[cn];
    }

    // ---- phase 2: exp / mask / S / A-fragments ----
    union { f16x8 v; unsigned u[4]; } af[2];
#pragma unroll
    for (int p = 0; p < 4; ++p) {
      const unsigned b0 = (m8 >> (2 * p)) & 1u;
      const unsigned b1 = (m8 >> (2 * p + 1)) & 1u;
#pragma unroll
      for (int h = 0; h < 2; ++h) {
        float lo = (float)arg[h][p][0];
        float hi = (float)arg[h][p][1];
        float e0 = b0 ? EXP2F(lo) : 0.f;                 // v_cndmask
        float e1 = b1 ? EXP2F(hi) : 0.f;
        S[h] += e0 + e1;
        union { hh2 r; unsigned u; } cv;
        cv.r = __builtin_amdgcn_cvt_pkrtz(e0, e1);       // exact 0 for masked
        af[h].u[p] = cv.u;
      }
    }

#pragma unroll
    for (int h = 0; h < 2; ++h) {
      acc[h][0] = __builtin_amdgcn_mfma_f32_16x16x32_f16(af[h].v, h ? b10 : b00, acc[h][0], 0, 0, 0);
      acc[h][1] = __builtin_amdgcn_mfma_f32_16x16x32_f16(af[h].v, h ? b11 : b01, acc[h][1], 0, 0, 0);
    }
  }

  // reduce S across quads (lanes il, il+16, il+32, il+48)
#pragma unroll
  for (int h = 0; h < 2; ++h) {
    float v = S[h];
    v += __shfl_xor(v, 16, 64);
    v += __shfl_xor(v, 32, 64);
    if (quad == 0) atomicAdd(&Sbuf[il][h], v);
  }
  // accumulate O partials: C/D layout row = quad*4+r (i), col = il (d half)
#pragma unroll
  for (int h = 0; h < 2; ++h)
#pragma unroll
    for (int dh = 0; dh < 2; ++dh)
#pragma unroll
      for (int r = 0; r < 4; ++r)
        atomicAdd(&Obuf[quad * 4 + r][h * DC + dh * 16 + il], acc[h][dh][r]);
  __syncthreads();

  // epilogue: divide by softmax denom, coalesced store
  for (int idx = tid; idx < 16 * 64; idx += 256) {
    int row = idx >> 6;
    int colg = idx & 63;
    out[(size_t)(ibase + row) * OC + hg * 64 + colg] =
        Obuf[row][colg] / Sbuf[row][colg >> 5];
  }
}

// ---------------------------------------------------------------------------
extern "C" void kernel_launch(void* const* d_in, const int* in_sizes, int n_in,
                              void* d_out, int out_size, void* d_ws, size_t ws_size,
                              hipStream_t stream) {
  const float* x    = (const float*)d_in[0];
  // d_in[1] = positions — unused by the reference
  const float* cfeat= (const float*)d_in[2];
  const int*   adj  = (const int*)d_in[3];
  const float* W    = (const float*)d_in[4];
  const float* a_l  = (const float*)d_in[5];
  const float* a_r  = (const float*)d_in[6];
  const float* Wc   = (const float*)d_in[7];
  const float* gate = (const float*)d_in[8];
  float* out = (float*)d_out;

  char* ws = (char*)d_ws;
  f16_t*    hT2  = (f16_t*)ws;                               // 2 MB
  unsigned* adjb = (unsigned*)(ws + (2u << 20));             // 2 MB
  float*    e_l2 = (float*)(ws + (4u << 20));                // 128 KB
  float*    cfT  = (float*)(ws + (4u << 20) + (128u << 10)); // 96 KB
  float*    Wc2  = (float*)(ws + (4u << 20) + (256u << 10)); // 192 B
  f16_t*    cfP  = (f16_t*)(ws + (4u << 20) + (320u << 10)); // 48 KB
  f16_t*    erP  = (f16_t*)(ws + (4u << 20) + (384u << 10)); // 64 KB

  prep_all<<<2560, 256, 0, stream>>>(x, W, a_l, a_r, adj, cfeat, Wc, gate,
                                     e_l2, erP, hT2, adjb, cfT, cfP, Wc2);
  attn<<<dim3(NN / 16, 4), 256, 0, stream>>>(adjb, e_l2, cfT, Wc2,
                                             (const u32x4*)cfP, (const u32x4*)erP,
                                             hT2, out);
}